// Round 7
// baseline (566.295 us; speedup 1.0000x reference)
//
#include <hip/hip_runtime.h>
#include <hip/hip_bf16.h>
#include <stdint.h>

using bf16 = __hip_bfloat16;
typedef __attribute__((ext_vector_type(8))) short short8;
typedef __attribute__((ext_vector_type(4))) short short4v;
typedef __attribute__((ext_vector_type(4))) float f32x4;

#define MFMA16(a, b, c) __builtin_amdgcn_mfma_f32_16x16x32_bf16((a), (b), (c), 0, 0, 0)

// k=16 MFMA for PV: A-frag k-layout (k=l4*4+e) matches scores D-layout in-register.
#if __has_builtin(__builtin_amdgcn_mfma_f32_16x16x16bf16_1k)
#define MFMAK16(a, b, c) __builtin_amdgcn_mfma_f32_16x16x16bf16_1k((a), (b), (c), 0, 0, 0)
#elif __has_builtin(__builtin_amdgcn_mfma_f32_16x16x16_bf16_1k)
#define MFMAK16(a, b, c) __builtin_amdgcn_mfma_f32_16x16x16_bf16_1k((a), (b), (c), 0, 0, 0)
#elif __has_builtin(__builtin_amdgcn_mfma_f32_16x16x16_bf16)
#define MFMAK16(a, b, c) __builtin_amdgcn_mfma_f32_16x16x16_bf16((a), (b), (c), 0, 0, 0)
#else
static __device__ __forceinline__ f32x4 mfmak16_asm(short4v a, short4v b, f32x4 c) {
  f32x4 d;
  asm("v_mfma_f32_16x16x16_bf16 %0, %1, %2, %3" : "=v"(d) : "v"(a), "v"(b), "v"(c));
  return d;
}
#define MFMAK16(a, b, c) mfmak16_asm((a), (b), (c))
#endif

// 1/sqrt(2048) * log2(e): folded into Q so scores feed exp2 directly
static constexpr float SCLE = 0.031879358f;

__device__ __forceinline__ void g2l16(const void* g, void* l) {
  __builtin_amdgcn_global_load_lds((const __attribute__((address_space(1))) void*)g,
                                   (__attribute__((address_space(3))) void*)l, 16, 0, 0);
}

// swizzled fragment read: 16B slot (slot ^ (row&7)) of a 128B row
__device__ __forceinline__ short8 frag(const bf16* lds, int row, int slot) {
  return *(const short8*)((const char*)lds + row * 128 + (((slot ^ (row & 7)) & 7) << 4));
}

// ---------------- f32 -> bf16 convert (8 elems / thread) ----------------
__global__ __launch_bounds__(256) void cvt_kernel(const float* __restrict__ in,
                                                  bf16* __restrict__ out, int n8) {
  int i = blockIdx.x * 256 + threadIdx.x;
  if (i >= n8) return;
  float4 f0 = ((const float4*)in)[i * 2 + 0];
  float4 f1 = ((const float4*)in)[i * 2 + 1];
  bf16 t[8] = {__float2bfloat16(f0.x), __float2bfloat16(f0.y),
               __float2bfloat16(f0.z), __float2bfloat16(f0.w),
               __float2bfloat16(f1.x), __float2bfloat16(f1.y),
               __float2bfloat16(f1.z), __float2bfloat16(f1.w)};
  ((float4*)out)[i] = *(const float4*)t;
}

// ---------------- mask dtype detect: 1 if int32 {0,1}, 0 if bytes ----------------
__global__ void detect_kernel(const int* __restrict__ m, int* __restrict__ flag) {
  int v = m[threadIdx.x];
  unsigned long long ok = __ballot((v == 0) || (v == 1));
  if (threadIdx.x == 0) *flag = (ok == 0xFFFFFFFFFFFFFFFFULL) ? 1 : 0;
}

// ---------------- pack mask to bits: pm word w holds elems [32w,32w+32) ----------------
__global__ __launch_bounds__(256) void pack_kernel(const void* __restrict__ maskp,
                                                   const int* __restrict__ flagp,
                                                   uint32_t* __restrict__ pm) {
  const int i = blockIdx.x * 256 + threadIdx.x;  // group of 4 elems
  uint32_t nib;
  if (*flagp) {
    const int4 v = ((const int4*)maskp)[i];
    nib = (v.x != 0) | ((v.y != 0) << 1) | ((v.z != 0) << 2) | ((v.w != 0) << 3);
  } else {
    const uchar4 c = ((const uchar4*)maskp)[i];
    nib = (c.x != 0) | ((c.y != 0) << 1) | ((c.z != 0) << 2) | ((c.w != 0) << 3);
  }
  uint32_t w = nib << ((i & 7) * 4);
  w |= __shfl_xor(w, 1, 64);
  w |= __shfl_xor(w, 2, 64);
  w |= __shfl_xor(w, 4, 64);
  if ((threadIdx.x & 7) == 0) pm[i >> 3] = w;
}

// ---------------- GEMM 128x128, BK=32, double-buffered prefetch ----------------
// C[m,n] = sum_k A[m,k]*B[n,k]
template <int EPI>
__global__ __launch_bounds__(256) void gemm_bt_kernel(
    const bf16* __restrict__ A, const bf16* __restrict__ Bm, int N, int K,
    const float* __restrict__ bias0, const float* __restrict__ bias1,
    const float* __restrict__ bias2, void* __restrict__ outp) {
  __shared__ bf16 aLds[2][128 * 32];
  __shared__ bf16 bLds[2][128 * 32];
  const int tid = threadIdx.x;
  const int wave = tid >> 6, lane = tid & 63;
  const int l15 = lane & 15, l4 = lane >> 4;
  const int row0 = blockIdx.y << 7, col0 = blockIdx.x << 7;
  const int wm = (wave >> 1) << 6, wn = (wave & 1) << 6;

  f32x4 acc[4][4] = {};

  const int sr = tid >> 2;
  const int sc = (tid & 3) << 3;
  const bf16* ga = A + (size_t)(row0 + sr) * K + sc;
  const bf16* gb = Bm + (size_t)(col0 + sr) * K + sc;
  const size_t rK64 = (size_t)64 * K;

  auto stage = [&](int buf, int k0) {
    g2l16(ga + k0, &aLds[buf][wave * 512]);
    g2l16(ga + k0 + rK64, &aLds[buf][2048 + wave * 512]);
    g2l16(gb + k0, &bLds[buf][wave * 512]);
    g2l16(gb + k0 + rK64, &bLds[buf][2048 + wave * 512]);
  };

  stage(0, 0);
  __syncthreads();
  const int NT = K >> 5;
  for (int t = 0; t < NT; t++) {
    if (t + 1 < NT) stage((t + 1) & 1, (t + 1) << 5);  // prefetch next tile
    const bf16* la = aLds[t & 1];
    const bf16* lb = bLds[t & 1];
    short8 af[4], bfr[4];
#pragma unroll
    for (int i = 0; i < 4; i++)
      af[i] = *(const short8*)&la[(wm + i * 16 + l15) * 32 + l4 * 8];
#pragma unroll
    for (int i = 0; i < 4; i++)
      bfr[i] = *(const short8*)&lb[(wn + i * 16 + l15) * 32 + l4 * 8];
#pragma unroll
    for (int i = 0; i < 4; i++)
#pragma unroll
      for (int j = 0; j < 4; j++) acc[i][j] = MFMA16(af[i], bfr[j], acc[i][j]);
    __syncthreads();  // protects buf (t&1) for overwrite in t+1; drains prefetch
  }

  if (EPI == 0) {
#pragma unroll
    for (int j = 0; j < 4; j++) {
      const int gcol = col0 + wn + j * 16 + l15;
      const int which = gcol / 768;
      const int oo = gcol - which * 768;
      const float* bs = (which == 0) ? bias0 : ((which == 1) ? bias1 : bias2);
      const float bv = bs[oo];
      const int h = oo >> 6, d = oo & 63;
      if (which < 2) {
        // Q pre-scaled by SCLE so attention scores feed exp2 directly
        const float scl = (which == 0) ? SCLE : 1.0f;
        bf16* outb = (bf16*)outp + (size_t)which * 6291456;
#pragma unroll
        for (int i = 0; i < 4; i++) {
#pragma unroll
          for (int r = 0; r < 4; r++) {
            const int grow = row0 + wm + i * 16 + l4 * 4 + r;
            const int b = grow >> 11, s = grow & 2047;
            outb[((size_t)((b * 12 + h) * 2048 + s)) * 64 + d] =
                __float2bfloat16((acc[i][j][r] + bv) * scl);
          }
        }
      } else {  // V -> transposed layout Vt[bh][d][t]
        bf16* vt = (bf16*)outp + (size_t)2 * 6291456;
#pragma unroll
        for (int i = 0; i < 4; i++) {
          const int grow = row0 + wm + i * 16 + l4 * 4;
          const int b = grow >> 11, s = grow & 2047;
          bf16 t4[4];
#pragma unroll
          for (int r = 0; r < 4; r++) t4[r] = __float2bfloat16(acc[i][j][r] + bv);
          *(short4v*)&vt[((size_t)((b * 12 + h) * 64 + d)) * 2048 + s] =
              *(const short4v*)t4;
        }
      }
    }
  } else if (EPI == 1) {
    bf16* outb = (bf16*)outp;
#pragma unroll
    for (int j = 0; j < 4; j++) {
      const int gcol = col0 + wn + j * 16 + l15;
      const float bv = bias0[gcol];
#pragma unroll
      for (int i = 0; i < 4; i++)
#pragma unroll
        for (int r = 0; r < 4; r++) {
          const int grow = row0 + wm + i * 16 + l4 * 4 + r;
          float v = acc[i][j][r] + bv;
          v = v > 0.f ? v : 0.f;
          outb[(size_t)grow * N + gcol] = __float2bfloat16(v);
        }
    }
  } else {
    float* outf = (float*)outp;
#pragma unroll
    for (int j = 0; j < 4; j++) {
      const int gcol = col0 + wn + j * 16 + l15;
      const float bv = bias0[gcol];
#pragma unroll
      for (int i = 0; i < 4; i++)
#pragma unroll
        for (int r = 0; r < 4; r++) {
          const int grow = row0 + wm + i * 16 + l4 * 4 + r;
          outf[(size_t)grow * N + gcol] = acc[i][j][r] + bv;
        }
    }
  }
}

// ---------------- GEMM 64x128 (for FFN2: N=768 -> grid 6x128=768 blocks) ----------------
__global__ __launch_bounds__(256) void gemm_bt64_kernel(
    const bf16* __restrict__ A, const bf16* __restrict__ Bm, int N, int K,
    const float* __restrict__ bias0, float* __restrict__ outf) {
  __shared__ bf16 aLds[2][64 * 32];
  __shared__ bf16 bLds[2][128 * 32];
  const int tid = threadIdx.x;
  const int wave = tid >> 6, lane = tid & 63;
  const int l15 = lane & 15, l4 = lane >> 4;
  const int row0 = blockIdx.y << 6, col0 = blockIdx.x << 7;
  const int wm = (wave >> 1) << 5, wn = (wave & 1) << 6;

  f32x4 acc[2][4] = {};

  const int sr = tid >> 2;
  const int sc = (tid & 3) << 3;
  const bf16* ga = A + (size_t)(row0 + sr) * K + sc;
  const bf16* gb = Bm + (size_t)(col0 + sr) * K + sc;
  const size_t rK64 = (size_t)64 * K;

  auto stage = [&](int buf, int k0) {
    g2l16(ga + k0, &aLds[buf][wave * 512]);
    g2l16(gb + k0, &bLds[buf][wave * 512]);
    g2l16(gb + k0 + rK64, &bLds[buf][2048 + wave * 512]);
  };

  stage(0, 0);
  __syncthreads();
  const int NT = K >> 5;
  for (int t = 0; t < NT; t++) {
    if (t + 1 < NT) stage((t + 1) & 1, (t + 1) << 5);
    const bf16* la = aLds[t & 1];
    const bf16* lb = bLds[t & 1];
    short8 af[2], bfr[4];
#pragma unroll
    for (int i = 0; i < 2; i++)
      af[i] = *(const short8*)&la[(wm + i * 16 + l15) * 32 + l4 * 8];
#pragma unroll
    for (int j = 0; j < 4; j++)
      bfr[j] = *(const short8*)&lb[(wn + j * 16 + l15) * 32 + l4 * 8];
#pragma unroll
    for (int i = 0; i < 2; i++)
#pragma unroll
      for (int j = 0; j < 4; j++) acc[i][j] = MFMA16(af[i], bfr[j], acc[i][j]);
    __syncthreads();
  }

#pragma unroll
  for (int j = 0; j < 4; j++) {
    const int gcol = col0 + wn + j * 16 + l15;
    const float bv = bias0[gcol];
#pragma unroll
    for (int i = 0; i < 2; i++)
#pragma unroll
      for (int r = 0; r < 4; r++) {
        const int grow = row0 + wm + i * 16 + l4 * 4 + r;
        outf[(size_t)grow * N + gcol] = acc[i][j][r] + bv;
      }
  }
}

// ---------------- Z-pass + fused V-scale ----------------
// grid 1536 (XCD-swizzled). Block = 64 t-rows (wave owns 16). Streams s in
// 64-row LDS-staged tiles. Tail: scales Vt[:, block's t-range] by 1/Z in-place.
__global__ __launch_bounds__(256) void zsum_kernel(
    const bf16* __restrict__ Qb, const bf16* __restrict__ Kb,
    const uint32_t* __restrict__ pm, bf16* __restrict__ Vt) {
  __shared__ bf16 qLds[2][64 * 64];  // 16 KB
  __shared__ float zbuf[64];
  const int tid = threadIdx.x, wave = tid >> 6, lane = tid & 63;
  const int l15 = lane & 15, l4 = lane >> 4;
  const int srr = lane >> 3, sss = lane & 7;
  const int bid = blockIdx.x;
  const int swz = (bid & 7) * 192 + (bid >> 3);  // XCD-bijective (1536%8==0)
  const int bh = swz >> 5, ttile = swz & 31;
  const int b = bh / 12;
  const int t0 = (ttile << 6) + (wave << 4);  // wave's 16 t-rows
  const size_t qkBase = (size_t)bh * (2048 * 64);
  const bf16* Kp = Kb + qkBase;
  const bf16* Qp = Qb + qkBase;
  const uint32_t* pmB = pm + (size_t)b * 2048 * 64;
  const int widx = t0 >> 5;
  const int shft = (wave & 1) * 16 + l4 * 4;

  // K fragments in regs for the whole kernel (A-operand: row t = t0 + l15)
  short8 ak[2];
#pragma unroll
  for (int kc = 0; kc < 2; kc++)
    ak[kc] = *(const short8*)(Kp + (size_t)(t0 + l15) * 64 + kc * 32 + l4 * 8);

  auto stageQ = [&](int buf, int s0) {
#pragma unroll
    for (int p = 0; p < 2; p++) {
      const int r = p * 32 + wave * 8 + srr;
      g2l16(Qp + (size_t)(s0 + r) * 64 + ((sss ^ (r & 7)) << 3),
            &qLds[buf][p * 2048 + wave * 512]);
    }
  };

  f32x4 z = {};
  stageQ(0, 0);
  __syncthreads();

  for (int i = 0; i < 32; i++) {
    const int s0 = i << 6;
    if (i < 31) stageQ((i + 1) & 1, s0 + 64);  // async prefetch
    const bf16* qb = qLds[i & 1];
    uint32_t mw[4];
#pragma unroll
    for (int sf = 0; sf < 4; sf++)
      mw[sf] = pmB[(size_t)(s0 + sf * 16 + l15) * 64 + widx];
#pragma unroll
    for (int sf = 0; sf < 4; sf++) {
      const short8 q0 = frag(qb, sf * 16 + l15, l4);
      const short8 q1 = frag(qb, sf * 16 + l15, 4 + l4);
      __builtin_amdgcn_s_setprio(1);
      f32x4 cc = {};
      cc = MFMA16(ak[0], q0, cc);
      cc = MFMA16(ak[1], q1, cc);
      __builtin_amdgcn_s_setprio(0);
      const uint32_t bits = mw[sf] >> shft;
#pragma unroll
      for (int r = 0; r < 4; r++) {
        const float e = __builtin_amdgcn_exp2f(cc[r]);
        z[r] += ((bits >> r) & 1) ? 0.f : e;
      }
    }
    __syncthreads();
  }

#pragma unroll
  for (int r = 0; r < 4; r++) {
    float zz = z[r];
    zz += __shfl_xor(zz, 1, 64);
    zz += __shfl_xor(zz, 2, 64);
    zz += __shfl_xor(zz, 4, 64);
    zz += __shfl_xor(zz, 8, 64);
    if (l15 == 0) zbuf[(wave << 4) + (l4 << 2) + r] = 1.0f / zz;
  }
  __syncthreads();

  // scale Vt[bh][0..63][ttile*64 .. +64) in place
  const int t0blk = ttile << 6;
  const int drow = tid >> 2;
  const int tcol = (tid & 3) << 4;
  bf16* vp = Vt + (size_t)bh * (64 * 2048) + (size_t)drow * 2048 + t0blk + tcol;
  bf16 v[16];
  *(short8*)&v[0] = *(const short8*)vp;
  *(short8*)&v[8] = *(const short8*)(vp + 8);
#pragma unroll
  for (int j = 0; j < 16; j++)
    v[j] = __float2bfloat16(__bfloat162float(v[j]) * zbuf[tcol + j]);
  *(short8*)vp = *(const short8*)&v[0];
  *(short8*)(vp + 8) = *(const short8*)&v[8];
}

// ---------------- PV pass: scores in regs feed k=16 PV MFMA directly ----------------
// grid 768 (XCD-swizzled). Block = 128 s-rows (wave owns 32, 2 mf sub-blocks).
// Per 64-t chunk: K,Vt staged in double-buffered LDS; P never leaves registers.
__global__ __launch_bounds__(256, 4) void attn_pv_kernel(
    const bf16* __restrict__ Qb, const bf16* __restrict__ Kb,
    const bf16* __restrict__ Vt, const uint32_t* __restrict__ pm,
    float* __restrict__ aOut) {
  __shared__ bf16 kLds[2][64 * 64];  // [t][d] 16 KB
  __shared__ bf16 vLds[2][64 * 64];  // [d][t] 16 KB
  const int tid = threadIdx.x, wave = tid >> 6, lane = tid & 63;
  const int l15 = lane & 15, l4 = lane >> 4;
  const int srr = lane >> 3, sss = lane & 7;
  const int bid = blockIdx.x;
  const int swz = (bid & 7) * 96 + (bid >> 3);  // XCD-bijective (768%8==0)
  const int bh = swz >> 4, stile = swz & 15;
  const int b = bh / 12, h = bh - b * 12;
  const int s0 = (stile << 7) + (wave << 5);  // wave's 32 s-rows
  const size_t qkBase = (size_t)bh * (2048 * 64);
  const bf16* Kp = Kb + qkBase;
  const bf16* Qp = Qb + qkBase;
  const bf16* Vp = Vt + (size_t)bh * 64 * 2048;
  const uint32_t* pmB = pm + (size_t)b * 2048 * 64;

  auto stageKV = [&](int buf, int t0) {
#pragma unroll
    for (int p = 0; p < 2; p++) {
      const int r = p * 32 + wave * 8 + srr;
      g2l16(Kp + (size_t)(t0 + r) * 64 + ((sss ^ (r & 7)) << 3),
            &kLds[buf][p * 2048 + wave * 512]);
      g2l16(Vp + (size_t)r * 2048 + t0 + ((sss ^ (r & 7)) << 3),
            &vLds[buf][p * 2048 + wave * 512]);
    }
  };

  // Q fragments in registers (pre-scaled by SCLE)
  short8 qf[2][2];
#pragma unroll
  for (int mf = 0; mf < 2; mf++)
#pragma unroll
    for (int kc = 0; kc < 2; kc++)
      qf[mf][kc] = *(const short8*)(Qp + (size_t)(s0 + mf * 16 + l15) * 64 +
                                    kc * 32 + l4 * 8);

  f32x4 oacc[2][4] = {};
  stageKV(0, 0);
  __syncthreads();

  for (int i = 0; i < 32; i++) {
    const int t0 = i << 6;
    if (i < 31) stageKV((i + 1) & 1, t0 + 64);  // async prefetch
    const bf16* kb = kLds[i & 1];
    const bf16* vb = vLds[i & 1];
    uint2 mw[2];
#pragma unroll
    for (int mf = 0; mf < 2; mf++)
      mw[mf] = *(const uint2*)(pmB + (size_t)(s0 + mf * 16 + l15) * 64 + (t0 >> 5));

#pragma unroll
    for (int tf = 0; tf < 4; tf++) {  // 16 t-rows per step
      const int trow = tf * 16 + l15;
      const short8 a0 = frag(kb, trow, l4);
      const short8 a1 = frag(kb, trow, 4 + l4);
      short4v pa[2];
#pragma unroll
      for (int mf = 0; mf < 2; mf++) {
        __builtin_amdgcn_s_setprio(1);
        f32x4 cc = {};
        cc = MFMA16(a0, qf[mf][0], cc);
        cc = MFMA16(a1, qf[mf][1], cc);
        __builtin_amdgcn_s_setprio(0);
        const uint32_t bits =
            ((tf < 2) ? mw[mf].x : mw[mf].y) >> ((tf & 1) * 16 + l4 * 4);
        bf16 p4[4];
#pragma unroll
        for (int r = 0; r < 4; r++) {
          const float e = __builtin_amdgcn_exp2f(cc[r]);
          p4[r] = __float2bfloat16(((bits >> r) & 1) ? 0.f : e);
        }
        pa[mf] = *(const short4v*)p4;
      }
      // PV: k=16 MFMA; V b64 reads from swizzled vLds (4 accesses/bank floor)
      __builtin_amdgcn_s_setprio(1);
#pragma unroll
      for (int nf = 0; nf < 4; nf++) {
        const int vrow = nf * 16 + l15;
        const short4v bv = *(const short4v*)(
            (const char*)vb + vrow * 128 +
            ((((tf * 2 + (l4 >> 1)) ^ (vrow & 7)) & 7) << 4) + (l4 & 1) * 8);
        oacc[0][nf] = MFMAK16(pa[0], bv, oacc[0][nf]);
        oacc[1][nf] = MFMAK16(pa[1], bv, oacc[1][nf]);
      }
      __builtin_amdgcn_s_setprio(0);
    }
    __syncthreads();
  }

#pragma unroll
  for (int mf = 0; mf < 2; mf++)
#pragma unroll
    for (int nf = 0; nf < 4; nf++)
#pragma unroll
      for (int r = 0; r < 4; r++) {
        const int sg = s0 + mf * 16 + l4 * 4 + r;
        const int d = nf * 16 + l15;
        aOut[((size_t)(b * 2048 + sg)) * 768 + h * 64 + d] = oacc[mf][nf][r];
      }
}

// ---------------- LayerNorm + residual; OUTMODE 0: f32, 1: bf16 ----------------
template <int OUTMODE>
__global__ __launch_bounds__(256) void ln_kernel(const float* __restrict__ in,
                                                 const float* __restrict__ gamma,
                                                 const float* __restrict__ beta,
                                                 void* __restrict__ outp) {
  const int row = blockIdx.x, tid = threadIdx.x;
  const float* x = in + (size_t)row * 768;
  float v0 = x[tid], v1 = x[tid + 256], v2 = x[tid + 512];
  float s = v0 + v1 + v2;
#pragma unroll
  for (int m = 32; m >= 1; m >>= 1) s += __shfl_xor(s, m, 64);
  __shared__ float red[4];
  if ((tid & 63) == 0) red[tid >> 6] = s;
  __syncthreads();
  s = red[0] + red[1] + red[2] + red[3];
  const float mu = s * (1.f / 768.f);
  const float d0 = v0 - mu, d1 = v1 - mu, d2 = v2 - mu;
  float q = d0 * d0 + d1 * d1 + d2 * d2;
#pragma unroll
  for (int m = 32; m >= 1; m >>= 1) q += __shfl_xor(q, m, 64);
  __syncthreads();
  if ((tid & 63) == 0) red[tid >> 6] = q;
  __syncthreads();
  q = red[0] + red[1] + red[2] + red[3];
  const float rs = rsqrtf(q * (1.f / 768.f) + 1e-5f);
  const float y0 = d0 * rs * gamma[tid] + beta[tid] + v0;
  const float y1 = d1 * rs * gamma[tid + 256] + beta[tid + 256] + v1;
  const float y2 = d2 * rs * gamma[tid + 512] + beta[tid + 512] + v2;
  if (OUTMODE == 0) {
    float* o = (float*)outp + (size_t)row * 768;
    o[tid] = y0; o[tid + 256] = y1; o[tid + 512] = y2;
  } else {
    bf16* o = (bf16*)outp + (size_t)row * 768;
    o[tid] = __float2bfloat16(y0);
    o[tid + 256] = __float2bfloat16(y1);
    o[tid + 512] = __float2bfloat16(y2);
  }
}

extern "C" void kernel_launch(void* const* d_in, const int* in_sizes, int n_in,
                              void* d_out, int out_size, void* d_ws, size_t ws_size,
                              hipStream_t stream) {
  const float* x = (const float*)d_in[0];
  const void* mask = d_in[1];
  const float* Wq = (const float*)d_in[2];
  const float* bq = (const float*)d_in[3];
  const float* Wk = (const float*)d_in[4];
  const float* bk = (const float*)d_in[5];
  const float* Wv = (const float*)d_in[6];
  const float* bv = (const float*)d_in[7];
  const float* gamma = (const float*)d_in[8];
  const float* beta = (const float*)d_in[9];
  const float* W1 = (const float*)d_in[10];
  const float* b1 = (const float*)d_in[11];
  const float* W2 = (const float*)d_in[12];
  const float* b2 = (const float*)d_in[13];
  float* out = (float*)d_out;

  char* ws = (char*)d_ws;
  size_t o = 0;
  auto al = [&](size_t n) { size_t r = o; o = (o + n + 255) & ~(size_t)255; return r; };
  const size_t Q_off = al(12582912);   // Q bf16 [48][2048][64] (pre-scaled by SCLE)
  const size_t K_off = al(12582912);   // K
  const size_t V_off = al(12582912);   // Vt bf16 [48][64][2048]
  const size_t XB_off = al(12582912);  // x bf16
  const size_t WQKV_off = al(3538944); // Wq|Wk|Wv bf16 [2304][768]
  const size_t H_off = Q_off;          // FFN hidden aliases Q (dead by then)
  const size_t W1B_off = al(4718592);
  const size_t W2B_off = al(4718592);
  const size_t A_off = al(25165824);   // attn out f32 [8192][768]
  const size_t BF_off = A_off;         // FFN out f32 aliases A
  const size_t A2_off = al(12582912);  // LN1 out bf16
  const size_t FL_off = al(256);
  const size_t PM_off = al(2097152);   // packed mask [4][2048][64 u32]
  if (o > ws_size) return;

  bf16* Qb = (bf16*)(ws + Q_off);
  bf16* Kb = (bf16*)(ws + K_off);
  bf16* Vt = (bf16*)(ws + V_off);
  bf16* XB = (bf16*)(ws + XB_off);
  bf16* WQKV = (bf16*)(ws + WQKV_off);
  bf16* Hb = (bf16*)(ws + H_off);
  bf16* W1B = (bf16*)(ws + W1B_off);
  bf16* W2B = (bf16*)(ws + W2B_off);
  float* Af = (float*)(ws + A_off);
  float* Bf = (float*)(ws + BF_off);
  bf16* A2b = (bf16*)(ws + A2_off);
  int* flag = (int*)(ws + FL_off);
  uint32_t* pm = (uint32_t*)(ws + PM_off);

  cvt_kernel<<<3072, 256, 0, stream>>>(x, XB, 786432);
  cvt_kernel<<<288, 256, 0, stream>>>(Wq, WQKV, 73728);
  cvt_kernel<<<288, 256, 0, stream>>>(Wk, WQKV + 589824, 73728);
  cvt_kernel<<<288, 256, 0, stream>>>(Wv, WQKV + 2 * 589824, 73728);
  cvt_kernel<<<1152, 256, 0, stream>>>(W1, W1B, 294912);
  cvt_kernel<<<1152, 256, 0, stream>>>(W2, W2B, 294912);
  detect_kernel<<<1, 64, 0, stream>>>((const int*)mask, flag);
  pack_kernel<<<16384, 256, 0, stream>>>(mask, flag, pm);

  gemm_bt_kernel<0><<<dim3(18, 64), 256, 0, stream>>>(XB, WQKV, 2304, 768, bq, bk, bv, Qb);
  zsum_kernel<<<1536, 256, 0, stream>>>(Qb, Kb, pm, Vt);  // + fused V-scale
  attn_pv_kernel<<<768, 256, 0, stream>>>(Qb, Kb, Vt, pm, Af);
  ln_kernel<1><<<8192, 256, 0, stream>>>(Af, gamma, beta, A2b);
  gemm_bt_kernel<1><<<dim3(24, 64), 256, 0, stream>>>(A2b, W1B, 3072, 768, b1, nullptr, nullptr, Hb);
  gemm_bt64_kernel<<<dim3(6, 128), 256, 0, stream>>>(Hb, W2B, 768, 3072, b2, Bf);
  ln_kernel<0><<<8192, 256, 0, stream>>>(Bf, gamma, beta, out);
}

// Round 8
// 519.303 us; speedup vs baseline: 1.0905x; 1.0905x over previous
//
#include <hip/hip_runtime.h>
#include <hip/hip_bf16.h>
#include <stdint.h>

using bf16 = __hip_bfloat16;
typedef __attribute__((ext_vector_type(8))) short short8;
typedef __attribute__((ext_vector_type(4))) short short4v;
typedef __attribute__((ext_vector_type(4))) float f32x4;

#define MFMA16(a, b, c) __builtin_amdgcn_mfma_f32_16x16x32_bf16((a), (b), (c), 0, 0, 0)

// k=16 MFMA for PV: A-frag k-layout (k=l4*4+e) matches scores D-layout in-register.
#if __has_builtin(__builtin_amdgcn_mfma_f32_16x16x16bf16_1k)
#define MFMAK16(a, b, c) __builtin_amdgcn_mfma_f32_16x16x16bf16_1k((a), (b), (c), 0, 0, 0)
#elif __has_builtin(__builtin_amdgcn_mfma_f32_16x16x16_bf16_1k)
#define MFMAK16(a, b, c) __builtin_amdgcn_mfma_f32_16x16x16_bf16_1k((a), (b), (c), 0, 0, 0)
#elif __has_builtin(__builtin_amdgcn_mfma_f32_16x16x16_bf16)
#define MFMAK16(a, b, c) __builtin_amdgcn_mfma_f32_16x16x16_bf16((a), (b), (c), 0, 0, 0)
#else
static __device__ __forceinline__ f32x4 mfmak16_asm(short4v a, short4v b, f32x4 c) {
  f32x4 d;
  asm("v_mfma_f32_16x16x16_bf16 %0, %1, %2, %3" : "=v"(d) : "v"(a), "v"(b), "v"(c));
  return d;
}
#define MFMAK16(a, b, c) mfmak16_asm((a), (b), (c))
#endif

// 1/sqrt(2048) * log2(e): folded into Q so scores feed exp2 directly
static constexpr float SCLE = 0.031879358f;

__device__ __forceinline__ void g2l16(const void* g, void* l) {
  __builtin_amdgcn_global_load_lds((const __attribute__((address_space(1))) void*)g,
                                   (__attribute__((address_space(3))) void*)l, 16, 0, 0);
}

// swizzled fragment read: 16B slot (slot ^ (row&7)) of a 128B row
__device__ __forceinline__ short8 frag(const bf16* lds, int row, int slot) {
  return *(const short8*)((const char*)lds + row * 128 + (((slot ^ (row & 7)) & 7) << 4));
}

// ---------------- f32 -> bf16 convert (8 elems / thread) ----------------
__global__ __launch_bounds__(256) void cvt_kernel(const float* __restrict__ in,
                                                  bf16* __restrict__ out, int n8) {
  int i = blockIdx.x * 256 + threadIdx.x;
  if (i >= n8) return;
  float4 f0 = ((const float4*)in)[i * 2 + 0];
  float4 f1 = ((const float4*)in)[i * 2 + 1];
  bf16 t[8] = {__float2bfloat16(f0.x), __float2bfloat16(f0.y),
               __float2bfloat16(f0.z), __float2bfloat16(f0.w),
               __float2bfloat16(f1.x), __float2bfloat16(f1.y),
               __float2bfloat16(f1.z), __float2bfloat16(f1.w)};
  ((float4*)out)[i] = *(const float4*)t;
}

// ---------------- mask dtype detect: 1 if int32 {0,1}, 0 if bytes ----------------
__global__ void detect_kernel(const int* __restrict__ m, int* __restrict__ flag) {
  int v = m[threadIdx.x];
  unsigned long long ok = __ballot((v == 0) || (v == 1));
  if (threadIdx.x == 0) *flag = (ok == 0xFFFFFFFFFFFFFFFFULL) ? 1 : 0;
}

// ---------------- pack mask to bits ----------------
// pm  [b][s][w]: word covers t in [32w,32w+32) for query s  (attn_pv layout)
// pmT [b][w][s]: same word, transposed                       (zsum layout, coalesced)
__global__ __launch_bounds__(256) void pack_kernel(const void* __restrict__ maskp,
                                                   const int* __restrict__ flagp,
                                                   uint32_t* __restrict__ pm,
                                                   uint32_t* __restrict__ pmT) {
  const int i = blockIdx.x * 256 + threadIdx.x;  // group of 4 elems
  uint32_t nib;
  if (*flagp) {
    const int4 v = ((const int4*)maskp)[i];
    nib = (v.x != 0) | ((v.y != 0) << 1) | ((v.z != 0) << 2) | ((v.w != 0) << 3);
  } else {
    const uchar4 c = ((const uchar4*)maskp)[i];
    nib = (c.x != 0) | ((c.y != 0) << 1) | ((c.z != 0) << 2) | ((c.w != 0) << 3);
  }
  uint32_t w = nib << ((i & 7) * 4);
  w |= __shfl_xor(w, 1, 64);
  w |= __shfl_xor(w, 2, 64);
  w |= __shfl_xor(w, 4, 64);
  if ((threadIdx.x & 7) == 0) {
    const int iw = i >> 3;            // flat word index = (b*2048 + s)*64 + tw
    pm[iw] = w;
    const int b = iw >> 17;
    const int rem = iw & 131071;
    const int s = rem >> 6, tw = rem & 63;
    pmT[b * 131072 + tw * 2048 + s] = w;
  }
}

// ---------------- GEMM 128x128, BK=32, double-buffered prefetch ----------------
// C[m,n] = sum_k A[m,k]*B[n,k]
template <int EPI>
__global__ __launch_bounds__(256) void gemm_bt_kernel(
    const bf16* __restrict__ A, const bf16* __restrict__ Bm, int N, int K,
    const float* __restrict__ bias0, const float* __restrict__ bias1,
    const float* __restrict__ bias2, void* __restrict__ outp) {
  __shared__ bf16 aLds[2][128 * 32];
  __shared__ bf16 bLds[2][128 * 32];
  const int tid = threadIdx.x;
  const int wave = tid >> 6, lane = tid & 63;
  const int l15 = lane & 15, l4 = lane >> 4;
  const int row0 = blockIdx.y << 7, col0 = blockIdx.x << 7;
  const int wm = (wave >> 1) << 6, wn = (wave & 1) << 6;

  f32x4 acc[4][4] = {};

  const int sr = tid >> 2;
  const int sc = (tid & 3) << 3;
  const bf16* ga = A + (size_t)(row0 + sr) * K + sc;
  const bf16* gb = Bm + (size_t)(col0 + sr) * K + sc;
  const size_t rK64 = (size_t)64 * K;

  auto stage = [&](int buf, int k0) {
    g2l16(ga + k0, &aLds[buf][wave * 512]);
    g2l16(ga + k0 + rK64, &aLds[buf][2048 + wave * 512]);
    g2l16(gb + k0, &bLds[buf][wave * 512]);
    g2l16(gb + k0 + rK64, &bLds[buf][2048 + wave * 512]);
  };

  stage(0, 0);
  __syncthreads();
  const int NT = K >> 5;
  for (int t = 0; t < NT; t++) {
    if (t + 1 < NT) stage((t + 1) & 1, (t + 1) << 5);  // prefetch next tile
    const bf16* la = aLds[t & 1];
    const bf16* lb = bLds[t & 1];
    short8 af[4], bfr[4];
#pragma unroll
    for (int i = 0; i < 4; i++)
      af[i] = *(const short8*)&la[(wm + i * 16 + l15) * 32 + l4 * 8];
#pragma unroll
    for (int i = 0; i < 4; i++)
      bfr[i] = *(const short8*)&lb[(wn + i * 16 + l15) * 32 + l4 * 8];
#pragma unroll
    for (int i = 0; i < 4; i++)
#pragma unroll
      for (int j = 0; j < 4; j++) acc[i][j] = MFMA16(af[i], bfr[j], acc[i][j]);
    __syncthreads();  // protects buf (t&1) for overwrite in t+1; drains prefetch
  }

  if (EPI == 0) {
#pragma unroll
    for (int j = 0; j < 4; j++) {
      const int gcol = col0 + wn + j * 16 + l15;
      const int which = gcol / 768;
      const int oo = gcol - which * 768;
      const float* bs = (which == 0) ? bias0 : ((which == 1) ? bias1 : bias2);
      const float bv = bs[oo];
      const int h = oo >> 6, d = oo & 63;
      if (which < 2) {
        // Q pre-scaled by SCLE so attention scores feed exp2 directly
        const float scl = (which == 0) ? SCLE : 1.0f;
        bf16* outb = (bf16*)outp + (size_t)which * 6291456;
#pragma unroll
        for (int i = 0; i < 4; i++) {
#pragma unroll
          for (int r = 0; r < 4; r++) {
            const int grow = row0 + wm + i * 16 + l4 * 4 + r;
            const int b = grow >> 11, s = grow & 2047;
            outb[((size_t)((b * 12 + h) * 2048 + s)) * 64 + d] =
                __float2bfloat16((acc[i][j][r] + bv) * scl);
          }
        }
      } else {  // V -> transposed layout Vt[bh][d][t]
        bf16* vt = (bf16*)outp + (size_t)2 * 6291456;
#pragma unroll
        for (int i = 0; i < 4; i++) {
          const int grow = row0 + wm + i * 16 + l4 * 4;
          const int b = grow >> 11, s = grow & 2047;
          bf16 t4[4];
#pragma unroll
          for (int r = 0; r < 4; r++) t4[r] = __float2bfloat16(acc[i][j][r] + bv);
          *(short4v*)&vt[((size_t)((b * 12 + h) * 64 + d)) * 2048 + s] =
              *(const short4v*)t4;
        }
      }
    }
  } else if (EPI == 1) {
    bf16* outb = (bf16*)outp;
#pragma unroll
    for (int j = 0; j < 4; j++) {
      const int gcol = col0 + wn + j * 16 + l15;
      const float bv = bias0[gcol];
#pragma unroll
      for (int i = 0; i < 4; i++)
#pragma unroll
        for (int r = 0; r < 4; r++) {
          const int grow = row0 + wm + i * 16 + l4 * 4 + r;
          float v = acc[i][j][r] + bv;
          v = v > 0.f ? v : 0.f;
          outb[(size_t)grow * N + gcol] = __float2bfloat16(v);
        }
    }
  } else {
    float* outf = (float*)outp;
#pragma unroll
    for (int j = 0; j < 4; j++) {
      const int gcol = col0 + wn + j * 16 + l15;
      const float bv = bias0[gcol];
#pragma unroll
      for (int i = 0; i < 4; i++)
#pragma unroll
        for (int r = 0; r < 4; r++) {
          const int grow = row0 + wm + i * 16 + l4 * 4 + r;
          outf[(size_t)grow * N + gcol] = acc[i][j][r] + bv;
        }
    }
  }
}

// ---------------- GEMM 64x128 (for FFN2: N=768 -> grid 6x128=768 blocks) ----------------
__global__ __launch_bounds__(256) void gemm_bt64_kernel(
    const bf16* __restrict__ A, const bf16* __restrict__ Bm, int N, int K,
    const float* __restrict__ bias0, float* __restrict__ outf) {
  __shared__ bf16 aLds[2][64 * 32];
  __shared__ bf16 bLds[2][128 * 32];
  const int tid = threadIdx.x;
  const int wave = tid >> 6, lane = tid & 63;
  const int l15 = lane & 15, l4 = lane >> 4;
  const int row0 = blockIdx.y << 6, col0 = blockIdx.x << 7;
  const int wm = (wave >> 1) << 5, wn = (wave & 1) << 6;

  f32x4 acc[2][4] = {};

  const int sr = tid >> 2;
  const int sc = (tid & 3) << 3;
  const bf16* ga = A + (size_t)(row0 + sr) * K + sc;
  const bf16* gb = Bm + (size_t)(col0 + sr) * K + sc;
  const size_t rK64 = (size_t)64 * K;

  auto stage = [&](int buf, int k0) {
    g2l16(ga + k0, &aLds[buf][wave * 512]);
    g2l16(gb + k0, &bLds[buf][wave * 512]);
    g2l16(gb + k0 + rK64, &bLds[buf][2048 + wave * 512]);
  };

  stage(0, 0);
  __syncthreads();
  const int NT = K >> 5;
  for (int t = 0; t < NT; t++) {
    if (t + 1 < NT) stage((t + 1) & 1, (t + 1) << 5);
    const bf16* la = aLds[t & 1];
    const bf16* lb = bLds[t & 1];
    short8 af[2], bfr[4];
#pragma unroll
    for (int i = 0; i < 2; i++)
      af[i] = *(const short8*)&la[(wm + i * 16 + l15) * 32 + l4 * 8];
#pragma unroll
    for (int j = 0; j < 4; j++)
      bfr[j] = *(const short8*)&lb[(wn + j * 16 + l15) * 32 + l4 * 8];
#pragma unroll
    for (int i = 0; i < 2; i++)
#pragma unroll
      for (int j = 0; j < 4; j++) acc[i][j] = MFMA16(af[i], bfr[j], acc[i][j]);
    __syncthreads();
  }

#pragma unroll
  for (int j = 0; j < 4; j++) {
    const int gcol = col0 + wn + j * 16 + l15;
    const float bv = bias0[gcol];
#pragma unroll
    for (int i = 0; i < 2; i++)
#pragma unroll
      for (int r = 0; r < 4; r++) {
        const int grow = row0 + wm + i * 16 + l4 * 4 + r;
        outf[(size_t)grow * N + gcol] = acc[i][j][r] + bv;
      }
  }
}

// ---------------- Z-pass + fused V-scale (R6 geometry) ----------------
// grid 768 (XCD-swizzled). Block = 128 t-rows (wave owns 32 via tf=2). Streams
// s in 64-row double-buffered LDS tiles. Tail scales Vt[:, block's 128-t slice].
__global__ __launch_bounds__(256, 3) void zsum_kernel(
    const bf16* __restrict__ Qb, const bf16* __restrict__ Kb,
    const uint32_t* __restrict__ pmT, bf16* __restrict__ Vt) {
  __shared__ bf16 qLds[2][64 * 64];  // 16 KB
  __shared__ float zbuf[128];
  const int tid = threadIdx.x, wave = tid >> 6, lane = tid & 63;
  const int l15 = lane & 15, l4 = lane >> 4;
  const int srr = lane >> 3, sss = lane & 7;
  const int bid = blockIdx.x;
  const int swz = (bid & 7) * 96 + (bid >> 3);  // XCD-bijective (768%8==0)
  const int bh = swz >> 4, ttile = swz & 15;
  const int b = bh / 12;
  const int t0 = (ttile << 7) + (wave << 5);  // wave's 32 t-rows
  const size_t qkBase = (size_t)bh * (2048 * 64);
  const bf16* Kp = Kb + qkBase;
  const bf16* Qp = Qb + qkBase;
  // transposed mask: word (t0>>5) for query s at pmT[b][t0>>5][s] (coalesced in s)
  const uint32_t* pmW = pmT + (size_t)b * 131072 + (size_t)(t0 >> 5) * 2048;

  // K fragments in regs for the whole kernel
  short8 ak[2][2];
#pragma unroll
  for (int tf = 0; tf < 2; tf++)
#pragma unroll
    for (int kc = 0; kc < 2; kc++)
      ak[tf][kc] = *(const short8*)(Kp + (size_t)(t0 + tf * 16 + l15) * 64 +
                                    kc * 32 + l4 * 8);

  auto stageQ = [&](int buf, int s0) {
#pragma unroll
    for (int p = 0; p < 2; p++) {
      const int r = p * 32 + wave * 8 + srr;
      g2l16(Qp + (size_t)(s0 + r) * 64 + ((sss ^ (r & 7)) << 3),
            &qLds[buf][p * 2048 + wave * 512]);
    }
  };

  f32x4 z[2] = {};
  stageQ(0, 0);
  __syncthreads();

  for (int i = 0; i < 32; i++) {
    const int s0 = i << 6;
    if (i < 31) stageQ((i + 1) & 1, s0 + 64);  // async prefetch
    const bf16* qb = qLds[i & 1];
    uint32_t mw[4];
#pragma unroll
    for (int sf = 0; sf < 4; sf++) mw[sf] = pmW[s0 + sf * 16 + l15];
#pragma unroll
    for (int sf = 0; sf < 4; sf++) {
      const short8 q0 = frag(qb, sf * 16 + l15, l4);
      const short8 q1 = frag(qb, sf * 16 + l15, 4 + l4);
#pragma unroll
      for (int tf = 0; tf < 2; tf++) {
        __builtin_amdgcn_s_setprio(1);
        f32x4 cc = {};
        cc = MFMA16(ak[tf][0], q0, cc);
        cc = MFMA16(ak[tf][1], q1, cc);
        __builtin_amdgcn_s_setprio(0);
        const uint32_t bits = mw[sf] >> (tf * 16 + l4 * 4);
#pragma unroll
        for (int r = 0; r < 4; r++) {
          const float e = __builtin_amdgcn_exp2f(cc[r]);
          z[tf][r] += ((bits >> r) & 1) ? 0.f : e;
        }
      }
    }
    __syncthreads();
  }

#pragma unroll
  for (int tf = 0; tf < 2; tf++)
#pragma unroll
    for (int r = 0; r < 4; r++) {
      float zz = z[tf][r];
      zz += __shfl_xor(zz, 1, 64);
      zz += __shfl_xor(zz, 2, 64);
      zz += __shfl_xor(zz, 4, 64);
      zz += __shfl_xor(zz, 8, 64);
      if (l15 == 0) zbuf[(wave << 5) + (tf << 4) + (l4 << 2) + r] = 1.0f / zz;
    }
  __syncthreads();

  // scale Vt[bh][0..63][ttile*128 .. +128) in place
  const int tBase = ttile << 7;
  const int drow = tid >> 2;        // 0..63
  const int tcol = (tid & 3) << 5;  // 0,32,64,96
  bf16* vp = Vt + (size_t)bh * (64 * 2048) + (size_t)drow * 2048 + tBase + tcol;
#pragma unroll
  for (int c = 0; c < 4; c++) {
    bf16 v[8];
    *(short8*)v = *(const short8*)(vp + c * 8);
#pragma unroll
    for (int j = 0; j < 8; j++)
      v[j] = __float2bfloat16(__bfloat162float(v[j]) * zbuf[tcol + c * 8 + j]);
    *(short8*)(vp + c * 8) = *(const short8*)v;
  }
}

// ---------------- PV pass: scores in regs feed k=16 PV MFMA directly ----------------
// grid 768 (XCD-swizzled). Block = 128 s-rows (wave owns 32, 2 mf sub-blocks).
// Per 64-t chunk: K,Vt staged in double-buffered LDS; P never leaves registers.
__global__ __launch_bounds__(256, 4) void attn_pv_kernel(
    const bf16* __restrict__ Qb, const bf16* __restrict__ Kb,
    const bf16* __restrict__ Vt, const uint32_t* __restrict__ pm,
    float* __restrict__ aOut) {
  __shared__ bf16 kLds[2][64 * 64];  // [t][d] 16 KB
  __shared__ bf16 vLds[2][64 * 64];  // [d][t] 16 KB
  const int tid = threadIdx.x, wave = tid >> 6, lane = tid & 63;
  const int l15 = lane & 15, l4 = lane >> 4;
  const int srr = lane >> 3, sss = lane & 7;
  const int bid = blockIdx.x;
  const int swz = (bid & 7) * 96 + (bid >> 3);  // XCD-bijective (768%8==0)
  const int bh = swz >> 4, stile = swz & 15;
  const int b = bh / 12, h = bh - b * 12;
  const int s0 = (stile << 7) + (wave << 5);  // wave's 32 s-rows
  const size_t qkBase = (size_t)bh * (2048 * 64);
  const bf16* Kp = Kb + qkBase;
  const bf16* Qp = Qb + qkBase;
  const bf16* Vp = Vt + (size_t)bh * 64 * 2048;
  const uint32_t* pmB = pm + (size_t)b * 2048 * 64;

  auto stageKV = [&](int buf, int t0) {
#pragma unroll
    for (int p = 0; p < 2; p++) {
      const int r = p * 32 + wave * 8 + srr;
      g2l16(Kp + (size_t)(t0 + r) * 64 + ((sss ^ (r & 7)) << 3),
            &kLds[buf][p * 2048 + wave * 512]);
      g2l16(Vp + (size_t)r * 2048 + t0 + ((sss ^ (r & 7)) << 3),
            &vLds[buf][p * 2048 + wave * 512]);
    }
  };

  // Q fragments in registers (pre-scaled by SCLE)
  short8 qf[2][2];
#pragma unroll
  for (int mf = 0; mf < 2; mf++)
#pragma unroll
    for (int kc = 0; kc < 2; kc++)
      qf[mf][kc] = *(const short8*)(Qp + (size_t)(s0 + mf * 16 + l15) * 64 +
                                    kc * 32 + l4 * 8);

  f32x4 oacc[2][4] = {};
  stageKV(0, 0);
  __syncthreads();

  for (int i = 0; i < 32; i++) {
    const int t0 = i << 6;
    if (i < 31) stageKV((i + 1) & 1, t0 + 64);  // async prefetch
    const bf16* kb = kLds[i & 1];
    const bf16* vb = vLds[i & 1];
    uint2 mw[2];
#pragma unroll
    for (int mf = 0; mf < 2; mf++)
      mw[mf] = *(const uint2*)(pmB + (size_t)(s0 + mf * 16 + l15) * 64 + (t0 >> 5));

#pragma unroll
    for (int tf = 0; tf < 4; tf++) {  // 16 t-rows per step
      const int trow = tf * 16 + l15;
      const short8 a0 = frag(kb, trow, l4);
      const short8 a1 = frag(kb, trow, 4 + l4);
      short4v pa[2];
#pragma unroll
      for (int mf = 0; mf < 2; mf++) {
        __builtin_amdgcn_s_setprio(1);
        f32x4 cc = {};
        cc = MFMA16(a0, qf[mf][0], cc);
        cc = MFMA16(a1, qf[mf][1], cc);
        __builtin_amdgcn_s_setprio(0);
        const uint32_t bits =
            ((tf < 2) ? mw[mf].x : mw[mf].y) >> ((tf & 1) * 16 + l4 * 4);
        bf16 p4[4];
#pragma unroll
        for (int r = 0; r < 4; r++) {
          const float e = __builtin_amdgcn_exp2f(cc[r]);
          p4[r] = __float2bfloat16(((bits >> r) & 1) ? 0.f : e);
        }
        pa[mf] = *(const short4v*)p4;
      }
      // PV: k=16 MFMA; V b64 reads from swizzled vLds (4 accesses/bank floor)
      __builtin_amdgcn_s_setprio(1);
#pragma unroll
      for (int nf = 0; nf < 4; nf++) {
        const int vrow = nf * 16 + l15;
        const short4v bv = *(const short4v*)(
            (const char*)vb + vrow * 128 +
            ((((tf * 2 + (l4 >> 1)) ^ (vrow & 7)) & 7) << 4) + (l4 & 1) * 8);
        oacc[0][nf] = MFMAK16(pa[0], bv, oacc[0][nf]);
        oacc[1][nf] = MFMAK16(pa[1], bv, oacc[1][nf]);
      }
      __builtin_amdgcn_s_setprio(0);
    }
    __syncthreads();
  }

#pragma unroll
  for (int mf = 0; mf < 2; mf++)
#pragma unroll
    for (int nf = 0; nf < 4; nf++)
#pragma unroll
      for (int r = 0; r < 4; r++) {
        const int sg = s0 + wave * 0 + mf * 16 + l4 * 4 + r;
        const int d = nf * 16 + l15;
        aOut[((size_t)(b * 2048 + sg)) * 768 + h * 64 + d] = oacc[mf][nf][r];
      }
}

// ---------------- LayerNorm + residual; OUTMODE 0: f32, 1: bf16 ----------------
template <int OUTMODE>
__global__ __launch_bounds__(256) void ln_kernel(const float* __restrict__ in,
                                                 const float* __restrict__ gamma,
                                                 const float* __restrict__ beta,
                                                 void* __restrict__ outp) {
  const int row = blockIdx.x, tid = threadIdx.x;
  const float* x = in + (size_t)row * 768;
  float v0 = x[tid], v1 = x[tid + 256], v2 = x[tid + 512];
  float s = v0 + v1 + v2;
#pragma unroll
  for (int m = 32; m >= 1; m >>= 1) s += __shfl_xor(s, m, 64);
  __shared__ float red[4];
  if ((tid & 63) == 0) red[tid >> 6] = s;
  __syncthreads();
  s = red[0] + red[1] + red[2] + red[3];
  const float mu = s * (1.f / 768.f);
  const float d0 = v0 - mu, d1 = v1 - mu, d2 = v2 - mu;
  float q = d0 * d0 + d1 * d1 + d2 * d2;
#pragma unroll
  for (int m = 32; m >= 1; m >>= 1) q += __shfl_xor(q, m, 64);
  __syncthreads();
  if ((tid & 63) == 0) red[tid >> 6] = q;
  __syncthreads();
  q = red[0] + red[1] + red[2] + red[3];
  const float rs = rsqrtf(q * (1.f / 768.f) + 1e-5f);
  const float y0 = d0 * rs * gamma[tid] + beta[tid] + v0;
  const float y1 = d1 * rs * gamma[tid + 256] + beta[tid + 256] + v1;
  const float y2 = d2 * rs * gamma[tid + 512] + beta[tid + 512] + v2;
  if (OUTMODE == 0) {
    float* o = (float*)outp + (size_t)row * 768;
    o[tid] = y0; o[tid + 256] = y1; o[tid + 512] = y2;
  } else {
    bf16* o = (bf16*)outp + (size_t)row * 768;
    o[tid] = __float2bfloat16(y0);
    o[tid + 256] = __float2bfloat16(y1);
    o[tid + 512] = __float2bfloat16(y2);
  }
}

extern "C" void kernel_launch(void* const* d_in, const int* in_sizes, int n_in,
                              void* d_out, int out_size, void* d_ws, size_t ws_size,
                              hipStream_t stream) {
  const float* x = (const float*)d_in[0];
  const void* mask = d_in[1];
  const float* Wq = (const float*)d_in[2];
  const float* bq = (const float*)d_in[3];
  const float* Wk = (const float*)d_in[4];
  const float* bk = (const float*)d_in[5];
  const float* Wv = (const float*)d_in[6];
  const float* bv = (const float*)d_in[7];
  const float* gamma = (const float*)d_in[8];
  const float* beta = (const float*)d_in[9];
  const float* W1 = (const float*)d_in[10];
  const float* b1 = (const float*)d_in[11];
  const float* W2 = (const float*)d_in[12];
  const float* b2 = (const float*)d_in[13];
  float* out = (float*)d_out;

  char* ws = (char*)d_ws;
  size_t o = 0;
  auto al = [&](size_t n) { size_t r = o; o = (o + n + 255) & ~(size_t)255; return r; };
  const size_t Q_off = al(12582912);   // Q bf16 [48][2048][64] (pre-scaled by SCLE)
  const size_t K_off = al(12582912);   // K
  const size_t V_off = al(12582912);   // Vt bf16 [48][64][2048]
  const size_t XB_off = al(12582912);  // x bf16
  const size_t WQKV_off = al(3538944); // Wq|Wk|Wv bf16 [2304][768]
  const size_t H_off = Q_off;          // FFN hidden aliases Q (dead by then)
  const size_t W1B_off = al(4718592);
  const size_t W2B_off = al(4718592);
  const size_t A_off = al(25165824);   // attn out f32 [8192][768]
  const size_t BF_off = A_off;         // FFN out f32 aliases A
  const size_t A2_off = al(12582912);  // LN1 out bf16
  const size_t FL_off = al(256);
  const size_t PM_off = al(2097152);   // packed mask [4][2048][64 u32]
  const size_t PMT_off = al(2097152);  // transposed packed mask [4][64][2048 u32]
  if (o > ws_size) return;

  bf16* Qb = (bf16*)(ws + Q_off);
  bf16* Kb = (bf16*)(ws + K_off);
  bf16* Vt = (bf16*)(ws + V_off);
  bf16* XB = (bf16*)(ws + XB_off);
  bf16* WQKV = (bf16*)(ws + WQKV_off);
  bf16* Hb = (bf16*)(ws + H_off);
  bf16* W1B = (bf16*)(ws + W1B_off);
  bf16* W2B = (bf16*)(ws + W2B_off);
  float* Af = (float*)(ws + A_off);
  float* Bf = (float*)(ws + BF_off);
  bf16* A2b = (bf16*)(ws + A2_off);
  int* flag = (int*)(ws + FL_off);
  uint32_t* pm = (uint32_t*)(ws + PM_off);
  uint32_t* pmT = (uint32_t*)(ws + PMT_off);

  cvt_kernel<<<3072, 256, 0, stream>>>(x, XB, 786432);
  cvt_kernel<<<288, 256, 0, stream>>>(Wq, WQKV, 73728);
  cvt_kernel<<<288, 256, 0, stream>>>(Wk, WQKV + 589824, 73728);
  cvt_kernel<<<288, 256, 0, stream>>>(Wv, WQKV + 2 * 589824, 73728);
  cvt_kernel<<<1152, 256, 0, stream>>>(W1, W1B, 294912);
  cvt_kernel<<<1152, 256, 0, stream>>>(W2, W2B, 294912);
  detect_kernel<<<1, 64, 0, stream>>>((const int*)mask, flag);
  pack_kernel<<<16384, 256, 0, stream>>>(mask, flag, pm, pmT);

  gemm_bt_kernel<0><<<dim3(18, 64), 256, 0, stream>>>(XB, WQKV, 2304, 768, bq, bk, bv, Qb);
  zsum_kernel<<<768, 256, 0, stream>>>(Qb, Kb, pmT, Vt);  // + fused V-scale
  attn_pv_kernel<<<768, 256, 0, stream>>>(Qb, Kb, Vt, pm, Af);
  ln_kernel<1><<<8192, 256, 0, stream>>>(Af, gamma, beta, A2b);
  gemm_bt_kernel<1><<<dim3(24, 64), 256, 0, stream>>>(A2b, W1B, 3072, 768, b1, nullptr, nullptr, Hb);
  gemm_bt64_kernel<<<dim3(6, 128), 256, 0, stream>>>(Hb, W2B, 768, 3072, b2, Bf);
  ln_kernel<0><<<8192, 256, 0, stream>>>(Bf, gamma, beta, out);
}